// Round 3
// baseline (778.450 us; speedup 1.0000x reference)
//
#include <hip/hip_runtime.h>
#include <math.h>

// Problem constants
#define NB   1024
#define NC   64
#define DIN  256
#define DH   128
#define DCP  32
#define NV   36

// Output flat offsets (fp32 elements), reference return order.
#define OFF0 0
#define OFF1 21233664
#define OFF2 23592960
#define OFF3 25952256
#define OFF4 26017792
#define OFF5 28377088
#define OFF6 28377089
#define OFF7 30474241

// FST: activations H^T then F^T, [128][36], XOR-swizzled columns.
// swizzle s(h) = ((h>>2)&7)*4: multiple of 4 -> 4-groups stay contiguous and
// 16B-aligned (b128-able); spreads banks for column-group writes.
#define FSTR 36
#define SWZ(h) ((((h) >> 2) & 7) << 2)

// LDS float-index layout: FST | R2 scratch union | R3 (CPS then M/PSIG/HB)
#define SM_FST 0               // 128*36 = 4608
#define SM_R2  4608            // scratch union, 3584 floats
#define SM_R3  8192            // 1088 floats
#define SM_TOT 9280            // 37120 B -> 4 blocks/CU

#define SM_XT  SM_R2           // A: [16][36] swizzled X^T chunk (576)
#define SM_W1C (SM_R2 + 576)   // A: [16][128] W1 chunk (2048)
#define SM_W2S SM_R2           // B: [32][32] W2 chunk (1024)
#define SM_WM  SM_R2           // C: [11][128] Wm chunk (1408)
#define SM_WH  SM_R2           // D2: [8][128] head-weight slots (1024)
#define SM_HD  (SM_R2 + 1024)  // D2: [32][80] head logits (2560)
#define SM_WD  SM_R2           // D4: [16][216] Wdyn chunk (3456)
#define SM_DYN SM_R2           // D4: [32][112] half-buffer (3584)
#define SM_CPS SM_R3           // [32][34] caps_params (B->C)
#define SM_M   SM_R3           // [32][6] ccr matrices (CPS dead)
#define SM_PSIG (SM_R3 + 192)  // [32]
#define SM_HB  (SM_R3 + 224)   // [80] head biases

__device__ __forceinline__ void gload16(const float* g, float* l) {
    // async global->LDS, 16B/lane; LDS dest must be wave-uniform base + lane*16
    __builtin_amdgcn_global_load_lds(
        (const __attribute__((address_space(1))) void*)g,
        (__attribute__((address_space(3))) void*)l, 16, 0, 0);
}

__device__ __forceinline__ float sigm(float x) { return 1.0f / (1.0f + __expf(-x)); }
__device__ __forceinline__ float tanh5(float x) {
    x = fminf(fmaxf(5.0f * x, -15.0f), 15.0f);
    float z = __expf(2.0f * x);
    return (z - 1.0f) / (z + 1.0f);
}
__device__ __forceinline__ void geo(const float* p, float* m) {
    float sx = sigm(p[0]) + 0.01f;
    float sy = sigm(p[1]) + 0.01f;
    float th = p[2] * 6.28318530717958647692f;
    float sh = tanh5(p[3]);
    float tx = tanh5(p[4]);
    float ty = tanh5(p[5]);
    float cc = __cosf(th), ss = __sinf(th);
    m[0] =  sx * cc + sh * sy * ss;
    m[1] = -sx * ss + sh * sy * cc;
    m[2] = tx;
    m[3] = sy * ss;
    m[4] = sy * cc;
    m[5] = ty;
}

__global__ void zero_l2_kernel(float* out) { out[OFF5] = 0.0f; }

__global__ __launch_bounds__(256, 4)
void caps_fused_kernel(const float* __restrict__ feat,
                       const float* __restrict__ w1,  const float* __restrict__ b1,
                       const float* __restrict__ w2,  const float* __restrict__ b2,
                       const float* __restrict__ wm,  const float* __restrict__ bm,
                       const float* __restrict__ wdy,
                       const float* __restrict__ wccr,const float* __restrict__ bccr,
                       const float* __restrict__ wpc, const float* __restrict__ bpc,
                       const float* __restrict__ wpv, const float* __restrict__ bpv,
                       const float* __restrict__ wsv, const float* __restrict__ bsv,
                       const float* __restrict__ cst,
                       float* __restrict__ out)
{
    __shared__ __align__(16) float sm[SM_TOT];
    const int t  = threadIdx.x;
    const int c  = blockIdx.y;
    const int rb = blockIdx.x * 32;

    // ===== Features passthrough (output 7): wave-contiguous full rows =====
    // float4 load + 4 scalar stores (R0 pattern: WRITE_SIZE was ideal).
#pragma unroll
    for (int p = 0; p < 8; ++p) {
        const int idx = t + p * 256;         // f4 index in 32x256 tile
        const int row = idx >> 6, c4 = idx & 63;
        const int gi = (rb + row) * (NC * DIN) + c * DIN + c4 * 4;
        const float4 v = *(const float4*)&feat[gi];
        float* o = &out[OFF7 + gi];
        o[0] = v.x; o[1] = v.y; o[2] = v.z; o[3] = v.w;
    }

    // ===== Phase A: H^T = relu(X @ W1 + b1)^T, 32x128, K=256, chunks of 16 =====
    {
        const int tx = t & 31;          // h-cols tx*4..+3
        const int ty = t >> 5;          // b-rows ty*4..+3
        float acc[4][4] = {};
        const int xrow = t >> 3, xk2 = (t & 7) * 2;
        for (int k0 = 0; k0 < DIN; k0 += 16) {
            __syncthreads();
            {   // stage X^T chunk [16][36] swizzled (2-way banks, free)
                const int gi = (rb + xrow) * (NC * DIN) + c * DIN + k0 + xk2;
                const float2 v = *(const float2*)&feat[gi];
                sm[SM_XT + xk2 * FSTR + (xrow ^ SWZ(xk2))]           = v.x;
                sm[SM_XT + (xk2 + 1) * FSTR + (xrow ^ SWZ(xk2 + 1))] = v.y;
            }
            // stage W1 chunk [16][128] via async global->LDS (2 x 16B/lane)
            gload16(&w1[c * (DIN * DH) + k0 * DH + t * 4],        &sm[SM_W1C + t * 4]);
            gload16(&w1[c * (DIN * DH) + k0 * DH + 1024 + t * 4], &sm[SM_W1C + 1024 + t * 4]);
            __syncthreads();
#pragma unroll
            for (int kk = 0; kk < 16; ++kk) {
                const float4 av = *(const float4*)&sm[SM_XT + kk * FSTR + ((ty * 4) ^ SWZ(kk))];
                const float4 bv = *(const float4*)&sm[SM_W1C + kk * DH + tx * 4];
                acc[0][0] += av.x * bv.x; acc[0][1] += av.x * bv.y; acc[0][2] += av.x * bv.z; acc[0][3] += av.x * bv.w;
                acc[1][0] += av.y * bv.x; acc[1][1] += av.y * bv.y; acc[1][2] += av.y * bv.z; acc[1][3] += av.y * bv.w;
                acc[2][0] += av.z * bv.x; acc[2][1] += av.z * bv.y; acc[2][2] += av.z * bv.z; acc[2][3] += av.z * bv.w;
                acc[3][0] += av.w * bv.x; acc[3][1] += av.w * bv.y; acc[3][2] += av.w * bv.z; acc[3][3] += av.w * bv.w;
            }
        }
        const float4 bb4 = *(const float4*)&b1[c * DH + tx * 4];
        const float bb[4] = { bb4.x, bb4.y, bb4.z, bb4.w };
        const int sH = (tx & 7) * 4;    // SWZ(tx*4+j) for j<4
#pragma unroll
        for (int j = 0; j < 4; ++j) {
            float4 w;
            w.x = fmaxf(acc[0][j] + bb[j], 0.0f);
            w.y = fmaxf(acc[1][j] + bb[j], 0.0f);
            w.z = fmaxf(acc[2][j] + bb[j], 0.0f);
            w.w = fmaxf(acc[3][j] + bb[j], 0.0f);
            *(float4*)&sm[SM_FST + (tx * 4 + j) * FSTR + ((ty * 4) ^ sH)] = w;
        }
    }

    // ===== Phase B: raw = relu(H @ W2 + b2), 32x32, K=128, chunks of 32 =====
    {
        const int b  = t & 31;
        const int j4 = (t >> 5) << 2;
        float acc[4] = {};
        for (int k0 = 0; k0 < DH; k0 += 32) {
            __syncthreads();
            gload16(&w2[c * (DH * DCP) + k0 * DCP + t * 4], &sm[SM_W2S + t * 4]);
            __syncthreads();
#pragma unroll
            for (int kk = 0; kk < 32; ++kk) {
                const int k = k0 + kk;
                const float h = sm[SM_FST + k * FSTR + (b ^ SWZ(k))];
                const float4 wv = *(const float4*)&sm[SM_W2S + kk * DCP + j4];
                acc[0] += h * wv.x; acc[1] += h * wv.y; acc[2] += h * wv.z; acc[3] += h * wv.w;
            }
        }
#pragma unroll
        for (int jj = 0; jj < 4; ++jj) {
            const float v = fmaxf(acc[jj] + b2[c * DCP + j4 + jj], 0.0f);
            out[OFF6 + ((rb + b) * NC + c) * DCP + j4 + jj] = v;
            sm[SM_CPS + b * 34 + j4 + jj] = v;
        }
        if (t < 32) sm[SM_CPS + t * 34 + 32] = 1.0f;
    }

    // ===== Phase C: F = relu(CP @ Wm + bm), 32x128, K=33, chunks of 11 =====
    {
        const int b  = t & 31;
        const int nb = (t >> 5) << 4;
        float acc[16] = {};
        for (int k0 = 0; k0 < 33; k0 += 11) {
            __syncthreads();
            gload16(&wm[c * (33 * DH) + k0 * DH + t * 4], &sm[SM_WM + t * 4]);
            if (t < 96)
                gload16(&wm[c * (33 * DH) + k0 * DH + 1024 + t * 4], &sm[SM_WM + 1024 + t * 4]);
            __syncthreads();
#pragma unroll
            for (int kk = 0; kk < 11; ++kk) {
                const float a = sm[SM_CPS + b * 34 + k0 + kk];
#pragma unroll
                for (int jq = 0; jq < 4; ++jq) {
                    const float4 wv = *(const float4*)&sm[SM_WM + kk * DH + nb + jq * 4];
                    acc[jq*4+0] += a * wv.x; acc[jq*4+1] += a * wv.y;
                    acc[jq*4+2] += a * wv.z; acc[jq*4+3] += a * wv.w;
                }
            }
        }
#pragma unroll
        for (int j = 0; j < 16; ++j) {
            const float v = fmaxf(acc[j] + bm[c * DH + nb + j], 0.0f);
            sm[SM_FST + (nb + j) * FSTR + (b ^ SWZ(nb + j))] = v;   // F^T overwrites H^T
        }
    }

    // ===== Phase D2: heads [ccr|pres_caps|pres_vote|scale_vote], 32x80, K=128 =====
    // Weight slots: [8][128], slot = grp*8 + j (j<5 valid), real col = grp*5+j.
    // Read = b128(4 cols) + b32(1 col) per kk; A-read = b64 row-pair.
    {
        const int txx = t & 15;   // col-group: real cols txx*5..+4
        const int tyy = t >> 4;   // rows tyy*2, tyy*2+1
        float acc[2][5] = {};
        for (int k0 = 0; k0 < DH; k0 += 8) {
            __syncthreads();
#pragma unroll
            for (int p = 0; p < 4; ++p) {
                const int idx = t + p * 256;         // 0..1023 slots
                const int kk = idx >> 7, slot = idx & 127;
                const int grp = slot >> 3, j = slot & 7;
                if (j < 5) {
                    const int col = grp * 5 + j;     // 0..79
                    const int kg = k0 + kk;
                    float v = 0.0f;
                    if (col < 6)        v = wccr[c * (DH * 6) + kg * 6 + col];
                    else if (col == 6)  v = wpc[c * DH + kg];
                    else if (col < 43)  v = wpv[c * (DH * NV) + kg * NV + (col - 7)];
                    else if (col < 79)  v = wsv[c * (DH * NV) + kg * NV + (col - 43)];
                    sm[SM_WH + kk * 128 + slot] = v;
                }
            }
            if (k0 == 0 && t < 80) {
                float v = 0.0f;
                if (t < 6)       v = bccr[c * 6 + t];
                else if (t == 6) v = bpc[c];
                else if (t < 43) v = bpv[c * NV + (t - 7)];
                else if (t < 79) v = bsv[c * NV + (t - 43)];
                sm[SM_HB + t] = v;
            }
            __syncthreads();
#pragma unroll
            for (int kk = 0; kk < 8; ++kk) {
                const int k = k0 + kk;
                const float2 a2 = *(const float2*)&sm[SM_FST + k * FSTR + ((tyy * 2) ^ SWZ(k))];
                const float4 w4 = *(const float4*)&sm[SM_WH + kk * 128 + txx * 8];
                const float  w5 = sm[SM_WH + kk * 128 + txx * 8 + 4];
                acc[0][0] += a2.x * w4.x; acc[0][1] += a2.x * w4.y; acc[0][2] += a2.x * w4.z;
                acc[0][3] += a2.x * w4.w; acc[0][4] += a2.x * w5;
                acc[1][0] += a2.y * w4.x; acc[1][1] += a2.y * w4.y; acc[1][2] += a2.y * w4.z;
                acc[1][3] += a2.y * w4.w; acc[1][4] += a2.y * w5;
            }
        }
#pragma unroll
        for (int i = 0; i < 2; ++i)
#pragma unroll
            for (int j = 0; j < 5; ++j)
                sm[SM_HD + (tyy * 2 + i) * 80 + txx * 5 + j] = acc[i][j];
    }
    __syncthreads();

    // D2b: ccr matrices + pres_caps sigmoid
    if (t < 32) {
        const int b = t;
        const float plc = sm[SM_HD + b * 80 + 6] + sm[SM_HB + 6];
        out[OFF3 + (rb + b) * NC + c] = plc;
        sm[SM_PSIG + b] = sigm(plc);
        float p[6], m[6];
#pragma unroll
        for (int i = 0; i < 6; ++i) p[i] = sm[SM_HD + b * 80 + i] + sm[SM_HB + i];
        geo(p, m);
#pragma unroll
        for (int i = 0; i < 6; ++i) sm[SM_M + b * 6 + i] = m[i];
    }
    __syncthreads();

    // D2c: pres_vote / scale_vote epilogues
#pragma unroll
    for (int p = 0; p < 10; ++p) {
        const int item = t + p * 256;
        const int b = item / 80, col = item % 80;
        if (col >= 7 && col < 79) {
            const float v = sm[SM_HD + b * 80 + col] + sm[SM_HB + col];
            const int base = ((rb + b) * NC + c) * NV;
            if (col < 43) {
                const int o = col - 7;
                out[OFF4 + base + o] = v;
                out[OFF2 + base + o] = sm[SM_PSIG + b] * sigm(v);
            } else {
                const int o = col - 43;
                float sp = v + 0.5f;
                sp = (sp > 15.0f) ? sp : log1pf(__expf(sp));
                out[OFF1 + base + o] = sp + 0.01f;
            }
        }
    }

    // ===== Phase D4: cpr_dynamic = F @ Wdyn, 32x216, K=128, chunks of 16 =====
    float l2loc = 0.0f;
    {
        const int g   = t & 63;    // col group 4g..4g+3; g>=54 idle (clamped reads)
        const int gc  = min(g, 53);
        const int ty4 = t >> 6;    // rows ty4*8..+7 (uniform per wave -> bcast A)
        float acc[8][4] = {};
        for (int k0 = 0; k0 < DH; k0 += 16) {
            __syncthreads();       // also protects HD/WH before WD overwrite
            {
                const int gb = c * (DH * 216) + k0 * 216;
                gload16(&wdy[gb + t * 4],        &sm[SM_WD + t * 4]);
                gload16(&wdy[gb + 1024 + t * 4], &sm[SM_WD + 1024 + t * 4]);
                gload16(&wdy[gb + 2048 + t * 4], &sm[SM_WD + 2048 + t * 4]);
                if (t < 96)
                    gload16(&wdy[gb + 3072 + t * 4], &sm[SM_WD + 3072 + t * 4]);
            }
            __syncthreads();
#pragma unroll
            for (int kk = 0; kk < 16; ++kk) {
                const int k = k0 + kk;
                const int rbase = (ty4 * 8) ^ SWZ(k);
                const float4 aA = *(const float4*)&sm[SM_FST + k * FSTR + rbase];       // rows +0..3
                const float4 aB = *(const float4*)&sm[SM_FST + k * FSTR + (rbase ^ 4)]; // rows +4..7
                const float4 w = *(const float4*)&sm[SM_WD + kk * 216 + gc * 4];
                acc[0][0] += aA.x * w.x; acc[0][1] += aA.x * w.y; acc[0][2] += aA.x * w.z; acc[0][3] += aA.x * w.w;
                acc[1][0] += aA.y * w.x; acc[1][1] += aA.y * w.y; acc[1][2] += aA.y * w.z; acc[1][3] += aA.y * w.w;
                acc[2][0] += aA.z * w.x; acc[2][1] += aA.z * w.y; acc[2][2] += aA.z * w.z; acc[2][3] += aA.z * w.w;
                acc[3][0] += aA.w * w.x; acc[3][1] += aA.w * w.y; acc[3][2] += aA.w * w.z; acc[3][3] += aA.w * w.w;
                acc[4][0] += aB.x * w.x; acc[4][1] += aB.x * w.y; acc[4][2] += aB.x * w.z; acc[4][3] += aB.x * w.w;
                acc[5][0] += aB.y * w.x; acc[5][1] += aB.y * w.y; acc[5][2] += aB.y * w.z; acc[5][3] += aB.y * w.w;
                acc[6][0] += aB.z * w.x; acc[6][1] += aB.z * w.y; acc[6][2] += aB.z * w.z; acc[6][3] += aB.z * w.w;
                acc[7][0] += aB.w * w.x; acc[7][1] += aB.w * w.y; acc[7][2] += aB.w * w.z; acc[7][3] += aB.w * w.w;
            }
        }
        // two halves of 108 cols (g 0..26 | 27..53): DYN [32][112] then epilogue
        for (int half = 0; half < 2; ++half) {
            __syncthreads();   // prior WD/DYN readers done
            if (g < 54 && (g >= 27) == (half == 1)) {
                const int cg = g * 4 - half * 108;
#pragma unroll
                for (int i = 0; i < 8; ++i) {
                    float4 v; v.x = acc[i][0]; v.y = acc[i][1]; v.z = acc[i][2]; v.w = acc[i][3];
                    *(float4*)&sm[SM_DYN + (ty4 * 8 + i) * 112 + cg] = v;
                }
            }
            __syncthreads();
#pragma unroll
            for (int p = 0; p < 3; ++p) {
                const int item = t + p * 256;
                if (item < 576) {
                    const int b = item / 18, vh = item % 18;
                    const int v = half * 18 + vh;
                    float dyn[6], pose[6], mB[6];
                    float ss = 0.0f;
#pragma unroll
                    for (int j = 0; j < 6; ++j) {
                        dyn[j] = sm[SM_DYN + b * 112 + vh * 6 + j];
                        ss += dyn[j] * dyn[j];
                        pose[j] = dyn[j] + cst[c * (NV * 6) + v * 6 + j];
                    }
                    l2loc += ss;
                    geo(pose, mB);
                    const float A0 = sm[SM_M + b * 6 + 0], A1 = sm[SM_M + b * 6 + 1];
                    const float A2 = sm[SM_M + b * 6 + 2], A3 = sm[SM_M + b * 6 + 3];
                    const float A4 = sm[SM_M + b * 6 + 4], A5 = sm[SM_M + b * 6 + 5];
                    const int ob = (((rb + b) * NC + c) * NV + v) * 9;
                    out[OFF0 + ob + 0] = A0 * mB[0] + A1 * mB[3];
                    out[OFF0 + ob + 1] = A0 * mB[1] + A1 * mB[4];
                    out[OFF0 + ob + 2] = A0 * mB[2] + A1 * mB[5] + A2;
                    out[OFF0 + ob + 3] = A3 * mB[0] + A4 * mB[3];
                    out[OFF0 + ob + 4] = A3 * mB[1] + A4 * mB[4];
                    out[OFF0 + ob + 5] = A3 * mB[2] + A4 * mB[5] + A5;
                    out[OFF0 + ob + 6] = 0.0f;
                    out[OFF0 + ob + 7] = 0.0f;
                    out[OFF0 + ob + 8] = 1.0f;
                }
            }
        }
    }

    // L2 scalar: wave reduce, one atomic per wave; /B/2 = /2048
    l2loc += __shfl_down(l2loc, 32, 64);
    l2loc += __shfl_down(l2loc, 16, 64);
    l2loc += __shfl_down(l2loc, 8, 64);
    l2loc += __shfl_down(l2loc, 4, 64);
    l2loc += __shfl_down(l2loc, 2, 64);
    l2loc += __shfl_down(l2loc, 1, 64);
    if ((t & 63) == 0) atomicAdd(&out[OFF5], l2loc * (1.0f / 2048.0f));
}

extern "C" void kernel_launch(void* const* d_in, const int* in_sizes, int n_in,
                              void* d_out, int out_size, void* d_ws, size_t ws_size,
                              hipStream_t stream)
{
    const float* feat = (const float*)d_in[0];
    const float* w1   = (const float*)d_in[1];
    const float* b1   = (const float*)d_in[2];
    const float* w2   = (const float*)d_in[3];
    const float* b2   = (const float*)d_in[4];
    const float* wm   = (const float*)d_in[5];
    const float* bm   = (const float*)d_in[6];
    const float* wdy  = (const float*)d_in[7];
    const float* wccr = (const float*)d_in[8];
    const float* bccr = (const float*)d_in[9];
    const float* wpc  = (const float*)d_in[10];
    const float* bpc  = (const float*)d_in[11];
    const float* wpv  = (const float*)d_in[12];
    const float* bpv  = (const float*)d_in[13];
    const float* wsv  = (const float*)d_in[14];
    const float* bsv  = (const float*)d_in[15];
    const float* cst  = (const float*)d_in[16];
    float* out = (float*)d_out;

    zero_l2_kernel<<<1, 1, 0, stream>>>(out);
    dim3 grid(NB / 32, NC);
    caps_fused_kernel<<<grid, 256, 0, stream>>>(feat, w1, b1, w2, b2, wm, bm, wdy,
                                                wccr, bccr, wpc, bpc, wpv, bpv,
                                                wsv, bsv, cst, out);
}